// Round 9
// baseline (183.522 us; speedup 1.0000x reference)
//
#include <hip/hip_runtime.h>
#include <hip/hip_bf16.h>
#include <math.h>

#define B_ 2
#define S_ 2048
#define D_ 1024
#define H_ 16
#define HKV_ 4
#define DH_ 64
#define NTOK (B_*S_)     // 4096
#define NQK 1280         // q(1024) + k(256) fused cols
#define NQKV 1536        // + v

typedef __attribute__((ext_vector_type(8))) short short8;
typedef __attribute__((ext_vector_type(4))) float floatx4;
typedef _Float16 half4f __attribute__((ext_vector_type(4)));
typedef _Float16 half8f __attribute__((ext_vector_type(8)));

__device__ __forceinline__ short f2bf(float f) {
    union { __hip_bfloat16 h; short s; } u;
    u.h = __float2bfloat16(f);
    return u.s;
}
__device__ __forceinline__ float bf2f(short s) {
    union { __hip_bfloat16 h; short t; } u;
    u.t = s;
    return __bfloat162float(u.h);
}
__device__ __forceinline__ short f2h(float f) {
    union { _Float16 h; short s; } u;
    u.h = (_Float16)f;
    return u.s;
}
__device__ __forceinline__ float h2f(short s) {
    union { _Float16 h; short t; } u;
    u.t = s;
    return (float)u.h;
}
// pack two floats to fp16x2 (RTZ) as raw u32
__device__ __forceinline__ unsigned pkrtz(float a, float b) {
    return __builtin_bit_cast(unsigned, __builtin_amdgcn_cvt_pkrtz(a, b));
}

__device__ __forceinline__ void gload_lds16(const void* g, void* l) {
    __builtin_amdgcn_global_load_lds(
        (const __attribute__((address_space(1))) void*)g,
        (__attribute__((address_space(3))) void*)l, 16, 0, 0);
}

// ---------------- fused prep: x->bf16 convert + 4 weight transposes --------
__global__ __launch_bounds__(256) void prep_kernel(
    const float* __restrict__ x,  const float* __restrict__ Wq,
    const float* __restrict__ Wk, const float* __restrict__ Wv,
    const float* __restrict__ Wo,
    short* __restrict__ xb, short* __restrict__ wt, short* __restrict__ woT)
{
    int bid = blockIdx.x;
    if (bid < 4096) {
        int i = bid * 256 + threadIdx.x;
        float4 v = ((const float4*)x)[i];
        short4 o = { f2bf(v.x), f2bf(v.y), f2bf(v.z), f2bf(v.w) };
        ((short4*)xb)[i] = o;
        return;
    }
    bid -= 4096;
    const float* src; short* dst; int N;
    if (bid < 1024)      { src = Wq; dst = wt;                        N = 1024; }
    else if (bid < 1280) { bid -= 1024; src = Wk; dst = wt + (size_t)1024 * 1024; N = 256; }
    else if (bid < 1536) { bid -= 1280; src = Wv; dst = wt + (size_t)1280 * 1024; N = 256; }
    else                 { bid -= 1536; src = Wo; dst = woT;          N = 1024; }
    __shared__ float t[32][33];
    int tiles_n = N / 32;
    int n0 = (bid % tiles_n) * 32, k0 = (bid / tiles_n) * 32;
    int tx = threadIdx.x & 31, ty = threadIdx.x >> 5;
    #pragma unroll
    for (int i = 0; i < 4; ++i)
        t[ty + 8 * i][tx] = src[(size_t)(k0 + ty + 8 * i) * N + n0 + tx];
    __syncthreads();
    #pragma unroll
    for (int i = 0; i < 4; ++i)
        dst[(size_t)(n0 + ty + 8 * i) * 1024 + k0 + tx] = f2bf(t[tx][ty + 8 * i]);
}

// ---------------- GEMM: C[M,N] = A[M,1024] @ Bt[N,1024]^T (bf16 MFMA) -------
// 64x128 tile, BK=32, 256 thr = 4 waves in N; wave 64x32 (acc 4x2).
// 3-stage LDS pipeline, vmcnt(3) (prefetch stays in flight across barrier).
// MODE 2 outputs fp16 (attention operand dtype); MODE 1 outputs fp32.
template<int MODE>
__global__ __launch_bounds__(256, 4) void gemm_tn_kernel(
    const short* __restrict__ A, const short* __restrict__ Bt,
    short* __restrict__ Cb, float* __restrict__ Cf, short* __restrict__ Ct,
    int ldc)
{
    __shared__ short As[3][64 * 32];
    __shared__ short Bs[3][128 * 32];
    const int K = 1024;
    const int tid = threadIdx.x;
    const int bm0 = blockIdx.y * 64;
    const int bn0 = blockIdx.x * 128;
    const int lane = tid & 63, wn = tid >> 6;
    const int lm = lane & 15, quad = lane >> 4;

    floatx4 acc[4][2] = {};

    const int r0  = tid >> 2;         // 0..63
    const int kb0 = (tid & 3) * 16;

    auto stage = [&](int kt, int buf) {
        const char* gaA = (const char*)A  + ((size_t)(bm0 + r0) * K + kt) * 2 + kb0;
        const char* gaB = (const char*)Bt + ((size_t)(bn0 + r0) * K + kt) * 2 + kb0;
        gload_lds16(gaA,                      (char*)As[buf] + tid * 16);
        gload_lds16(gaB,                      (char*)Bs[buf] + tid * 16);
        gload_lds16(gaB + (size_t)64 * K * 2, (char*)Bs[buf] + 4096 + tid * 16);
    };

    stage(0, 0);
    stage(32, 1);
    for (int kt = 0; kt < K; kt += 32) {
        const int it = kt >> 5;
        const int buf = it % 3;
        if (it < (K / 32) - 1) asm volatile("s_waitcnt vmcnt(3)" ::: "memory");
        else                   asm volatile("s_waitcnt vmcnt(0)" ::: "memory");
        asm volatile("s_barrier" ::: "memory");
        if (kt + 64 < K) stage(kt + 64, (it + 2) % 3);

        short8 af[4], bfr[2];
        #pragma unroll
        for (int mt = 0; mt < 4; ++mt)
            af[mt] = *(const short8*)&As[buf][(mt * 16 + lm) * 32 + quad * 8];
        #pragma unroll
        for (int nt = 0; nt < 2; ++nt)
            bfr[nt] = *(const short8*)&Bs[buf][(wn * 32 + nt * 16 + lm) * 32 + quad * 8];
        #pragma unroll
        for (int mt = 0; mt < 4; ++mt)
            #pragma unroll
            for (int nt = 0; nt < 2; ++nt)
                acc[mt][nt] = __builtin_amdgcn_mfma_f32_16x16x32_bf16(
                    af[mt], bfr[nt], acc[mt][nt], 0, 0, 0);
    }

    const int col_base = bn0 + wn * 32;
    if (MODE == 2 && bn0 >= NQK) {  // V tiles -> transposed fp16 store
        #pragma unroll
        for (int mt = 0; mt < 4; ++mt)
            #pragma unroll
            for (int nt = 0; nt < 2; ++nt) {
                int vcol = col_base + nt * 16 + lm - NQK;
                int row0 = bm0 + mt * 16 + quad * 4;
                short4 o = { f2h(acc[mt][nt][0]), f2h(acc[mt][nt][1]),
                             f2h(acc[mt][nt][2]), f2h(acc[mt][nt][3]) };
                *(short4*)&Ct[(size_t)vcol * NTOK + row0] = o;
            }
    } else if (MODE == 1) {
        #pragma unroll
        for (int mt = 0; mt < 4; ++mt)
            #pragma unroll
            for (int nt = 0; nt < 2; ++nt)
                #pragma unroll
                for (int r = 0; r < 4; ++r) {
                    int row = bm0 + mt * 16 + quad * 4 + r;
                    int col = col_base + nt * 16 + lm;
                    Cf[(size_t)row * ldc + col] = acc[mt][nt][r];
                }
    } else {
        #pragma unroll
        for (int mt = 0; mt < 4; ++mt)
            #pragma unroll
            for (int nt = 0; nt < 2; ++nt)
                #pragma unroll
                for (int r = 0; r < 4; ++r) {
                    int row = bm0 + mt * 16 + quad * 4 + r;
                    int col = col_base + nt * 16 + lm;
                    Cb[(size_t)row * ldc + col] = f2h(acc[mt][nt][r]);
                }
    }
}

// ---------------- RoPE in-place on K only (fp16): qkb cols [1024,1280) -----
__global__ __launch_bounds__(256) void ropek_kernel(short* __restrict__ x,
                                                    const int* __restrict__ poff)
{
    int idx = blockIdx.x * 256 + threadIdx.x;
    if (idx >= NTOK * 4 * 32) return;
    int p   = idx & 31;
    int hd  = (idx >> 5) & 3;
    int tok = idx >> 7;
    int s   = tok & (S_ - 1);
    float t = (float)(s + poff[0]);
    float invf = exp2f(-0.415241012f * (float)p);   // 10000^(-p/32)
    float ang = t * invf;
    float sn, c;
    sincosf(ang, &sn, &c);
    size_t base = (size_t)tok * NQK + 1024 + hd * 64 + p;
    float x1 = h2f(x[base]), x2 = h2f(x[base + 32]);
    x[base]      = f2h(x1 * c - x2 * sn);
    x[base + 32] = f2h(x2 * c + x1 * sn);
}

// ---------------- Flash attention v8: transpose-free (K=16 PV) -------------
// S^T = K@Q^T via 16x16x32_f16 (C-layout row = key = quad*4+reg).
// PV via 16x16x16_f16: B-operand k-index = quad*4+j  ==  C-layout row, so
// P^T goes MFMA->MFMA entirely in registers. No P LDS round trip at all.
// V A-frags are b64 LDS reads (swizzle keeps <=2-way bank aliasing: free).
__global__ __launch_bounds__(256, 5) void attn_kernel8(
    const short* __restrict__ qk,  // fp16 [NTOK][1280], q cols raw (rope here)
    const short* __restrict__ vT,  // fp16 [256][NTOK]
    short* __restrict__ attn,      // bf16 [NTOK][1024]
    float* __restrict__ Opart,     // [1024][64][64]
    float* __restrict__ lpart,     // [1024][64]
    const int* __restrict__ poff)
{
    __shared__ short Ks[2][64 * 64];
    __shared__ short Vs[2][64 * 64];

    const int tid = threadIdx.x;
    const int lane = tid & 63, w = tid >> 6;
    const int lm = lane & 15, quad = lane >> 4;
    const int lm7 = lm & 7, qh = quad >> 1, ql = quad & 1;

    const int jid = blockIdx.x;
    int bh, c, kt0, kt1, pslot;
    if (jid < 1024) {
        bh = jid & 31;
        int idx = jid >> 5;
        int cm = 15 - (idx >> 1);        // 15..0 -> c = 31..16 (big first)
        c = 16 + cm;
        int half = idx & 1;
        int h1 = (c + 2) >> 1;
        kt0 = half ? h1 : 0;
        kt1 = half ? (c + 1) : h1;
        pslot = (bh * 16 + cm) * 2 + half;
    } else {
        int j = jid - 1024;
        bh = j & 31;
        c = 15 - (j >> 5);               // 15..0 (big first)
        kt0 = 0; kt1 = c + 1; pslot = -1;
    }
    const int h = bh & 15, b = bh >> 4, g = h >> 2;
    const int r0 = (c * 4 + w) * 16;

    const short* qbase = qk + (size_t)b * S_ * NQK;
    const short* kptr  = qbase + 1024 + g * 64;
    const short* vptr  = vT + (size_t)g * 64 * NTOK + (size_t)b * S_;

    // ---- load Q (fp16) + fold RoPE and softmax scale in-register ----
    half8f Q0, Q1;
    {
        const _Float16* qrow = (const _Float16*)qbase + (size_t)(r0 + lm) * NQK + h * 64;
        half8f q0r = *(const half8f*)(qrow + quad * 8);
        half8f q1r = *(const half8f*)(qrow + 32 + quad * 8);
        const float qs = 0.125f * 1.44269504f;  // 1/sqrt(64)*log2(e)
        float t = (float)(r0 + lm + poff[0]);
        #pragma unroll
        for (int j = 0; j < 8; ++j) {
            int p = quad * 8 + j;
            float invf = exp2f(-0.415241012f * (float)p);
            float ang = t * invf;
            float sn, cs;
            sincosf(ang, &sn, &cs);
            float x1 = (float)q0r[j], x2 = (float)q1r[j];
            Q0[j] = (_Float16)(qs * (x1 * cs - x2 * sn));
            Q1[j] = (_Float16)(qs * (x2 * cs + x1 * sn));
        }
    }

    half4f ones4;
    #pragma unroll
    for (int i = 0; i < 4; ++i) ones4[i] = (_Float16)1.0f;

    floatx4 O[4] = {};
    floatx4 lacc = {};

    const int sr = tid >> 3;
    const int cc = tid & 7;

    auto stage = [&](int kt2, int buf2) {
        const int k0s = kt2 * 64;
        #pragma unroll
        for (int i = 0; i < 2; ++i) {
            int r  = i * 32 + sr;
            int gc = cc ^ (r & 7);   // LDS chunk slot cc holds global chunk gc
            gload_lds16(kptr + (size_t)(k0s + r) * NQK + gc * 8,
                        (char*)(&Ks[buf2][0]) + (i * 256 + tid) * 16);
            gload_lds16(vptr + (size_t)r * NTOK + k0s + gc * 8,
                        (char*)(&Vs[buf2][0]) + (i * 256 + tid) * 16);
        }
    };

    auto tile = [&](int kt, int buf, bool diag) {
        const int k0 = kt * 64;
        const _Float16* KsB = (const _Float16*)&Ks[buf][0];
        const _Float16* VsB = (const _Float16*)&Vs[buf][0];
        half4f P[4];
        // ---- S^T subtile st: rows = keys st*16+quad*4+r, col q=lm ----
        #pragma unroll
        for (int st = 0; st < 4; ++st) {
            const int row = st * 16 + lm;
            half8f kf0 = *(const half8f*)(KsB + row * 64 + ((quad ^ lm7) * 8));
            half8f kf1 = *(const half8f*)(KsB + row * 64 + (((4 + quad) ^ lm7) * 8));
            floatx4 s = {};
            s = __builtin_amdgcn_mfma_f32_16x16x32_f16(kf0, Q0, s, 0, 0, 0);
            s = __builtin_amdgcn_mfma_f32_16x16x32_f16(kf1, Q1, s, 0, 0, 0);
            float e0 = exp2f(s[0]), e1 = exp2f(s[1]);
            float e2 = exp2f(s[2]), e3 = exp2f(s[3]);
            if (diag) {
                int keyb = k0 + st * 16 + quad * 4;
                int qq = r0 + lm;
                if (keyb + 0 > qq) e0 = 0.f;
                if (keyb + 1 > qq) e1 = 0.f;
                if (keyb + 2 > qq) e2 = 0.f;
                if (keyb + 3 > qq) e3 = 0.f;
            }
            union { unsigned u[2]; half4f hv; } pu;
            pu.u[0] = pkrtz(e0, e1);
            pu.u[1] = pkrtz(e2, e3);
            P[st] = pu.hv;   // == PV B-operand for key-chunk kc=st (k=quad*4+j)
        }
        // ---- O^T += V^T @ P^T (K=16 MFMAs, P straight from registers) ----
        #pragma unroll
        for (int sto = 0; sto < 4; ++sto) {
            const int vrow = sto * 16 + lm;
            floatx4 o = O[sto];
            #pragma unroll
            for (int kc = 0; kc < 4; ++kc) {
                half4f vf = *(const half4f*)(VsB + vrow * 64 +
                               ((2 * kc + qh) ^ lm7) * 8 + ql * 4);
                o = __builtin_amdgcn_mfma_f32_16x16x16f16(vf, P[kc], o, 0, 0, 0);
            }
            O[sto] = o;
        }
        #pragma unroll
        for (int kc = 0; kc < 4; ++kc)
            lacc = __builtin_amdgcn_mfma_f32_16x16x16f16(ones4, P[kc], lacc, 0, 0, 0);
    };

    stage(kt0, 0);
    for (int kt = kt0; kt < kt1; ++kt) {
        const int buf = (kt - kt0) & 1;
        asm volatile("s_waitcnt vmcnt(0)" ::: "memory");
        asm volatile("s_barrier" ::: "memory");
        if (kt + 1 < kt1) stage(kt + 1, buf ^ 1);
        tile(kt, buf, kt == c);
    }

    if (pslot >= 0) {
        float* op = Opart + (size_t)pslot * 4096;
        #pragma unroll
        for (int st = 0; st < 4; ++st)
            #pragma unroll
            for (int r = 0; r < 4; ++r)
                op[(st * 16 + quad * 4 + r) * 64 + w * 16 + lm] = O[st][r];
        if (quad == 0) lpart[pslot * 64 + w * 16 + lm] = lacc[0];
        return;
    }
    // direct path: normalize by lacc[0] (= l[q=lm]); C-layout [d][q] stores
    // straight to attn[q][d] as short4 (d = st*16+quad*4+r contiguous).
    float linv = 1.0f / lacc[0];
    short* ob = attn + (size_t)(b * S_ + r0 + lm) * D_ + h * 64;
    #pragma unroll
    for (int st = 0; st < 4; ++st) {
        short4 o = { f2bf(O[st][0] * linv), f2bf(O[st][1] * linv),
                     f2bf(O[st][2] * linv), f2bf(O[st][3] * linv) };
        *(short4*)&ob[st * 16 + quad * 4] = o;
    }
}

// ---------------- merge split-k partials: 512 blocks (bh, cm) --------------
__global__ __launch_bounds__(256) void attn_merge_kernel(
    const float* __restrict__ Opart, const float* __restrict__ lpart,
    short* __restrict__ attn)
{
    __shared__ float Ot[64 * 65];
    __shared__ float ls[64];
    const int bid = blockIdx.x;
    const int bh = bid & 31, cm = bid >> 5;
    const int h = bh & 15, b = bh >> 4;
    const int c = 16 + cm;
    const int p0 = (bh * 16 + cm) * 2;
    const int tid = threadIdx.x;

    if (tid < 64)
        ls[tid] = lpart[p0 * 64 + tid] + lpart[(p0 + 1) * 64 + tid];
    __syncthreads();

    const float* o0 = Opart + (size_t)p0 * 4096;
    const float* o1 = o0 + 4096;
    int d = tid >> 2, q0 = (tid & 3) * 16;
    #pragma unroll
    for (int j = 0; j < 4; ++j) {
        int off = d * 64 + q0 + j * 4;
        float4 a = *(const float4*)(o0 + off);
        float4 bv = *(const float4*)(o1 + off);
        Ot[d * 65 + q0 + j * 4 + 0] = (a.x + bv.x) / ls[q0 + j * 4 + 0];
        Ot[d * 65 + q0 + j * 4 + 1] = (a.y + bv.y) / ls[q0 + j * 4 + 1];
        Ot[d * 65 + q0 + j * 4 + 2] = (a.z + bv.z) / ls[q0 + j * 4 + 2];
        Ot[d * 65 + q0 + j * 4 + 3] = (a.w + bv.w) / ls[q0 + j * 4 + 3];
    }
    __syncthreads();
    int q = tid & 63, db = tid >> 6;
    alignas(16) short vals[16];
    #pragma unroll
    for (int j = 0; j < 16; ++j)
        vals[j] = f2bf(Ot[(db * 16 + j) * 65 + q]);
    short* ob = attn + (size_t)(b * S_ + c * 64 + q) * D_ + h * 64 + db * 16;
    *(uint4*)ob     = *(const uint4*)&vals[0];
    *(uint4*)(ob+8) = *(const uint4*)&vals[8];
}

extern "C" void kernel_launch(void* const* d_in, const int* in_sizes, int n_in,
                              void* d_out, int out_size, void* d_ws, size_t ws_size,
                              hipStream_t stream) {
    const float* x  = (const float*)d_in[0];
    const float* Wq = (const float*)d_in[1];
    const float* Wk = (const float*)d_in[2];
    const float* Wv = (const float*)d_in[3];
    const float* Wo = (const float*)d_in[4];
    const int* poff = (const int*)d_in[5];
    float* out = (float*)d_out;

    short* xb  = (short*)d_ws;                      // [4096][1024] bf16
    short* wt  = xb  + (size_t)NTOK * D_;           // [1536][1024] bf16 Wqkv^T
    short* woT = wt  + (size_t)NQKV * D_;           // [1024][1024] bf16 Wo^T
    short* qkb = woT + (size_t)D_ * D_;             // [4096][1280] fp16
    short* vbT = qkb + (size_t)NTOK * NQK;          // [256][4096]  fp16
    short* ab  = vbT + (size_t)(HKV_*DH_) * NTOK;   // [4096][1024] bf16
    float* Opart = (float*)(ab + (size_t)NTOK * D_); // [1024][64][64] fp32
    float* lpart = Opart + (size_t)1024 * 4096;      // [1024][64] fp32

    prep_kernel<<<dim3(4096 + 1024 + 256 + 256 + 1024), 256, 0, stream>>>(
        x, Wq, Wk, Wv, Wo, xb, wt, woT);
    gemm_tn_kernel<2><<<dim3(NQKV / 128, NTOK / 64), 256, 0, stream>>>(
        xb, wt, qkb, nullptr, vbT, NQK);
    ropek_kernel<<<dim3(NTOK * 4 * 32 / 256), 256, 0, stream>>>(qkb, poff);
    attn_kernel8<<<dim3(1536), 256, 0, stream>>>(qkb, vbT, ab, Opart, lpart, poff);
    attn_merge_kernel<<<dim3(512), 256, 0, stream>>>(Opart, lpart, ab);
    gemm_tn_kernel<1><<<dim3(D_ / 128, NTOK / 64), 256, 0, stream>>>(
        ab, woT, nullptr, out, nullptr, D_);
}